// Round 1
// baseline (2498.110 us; speedup 1.0000x reference)
//
#include <hip/hip_runtime.h>
#include <hip/hip_bf16.h>
#include <math.h>

// Problem constants: N=64, L=1024, H=1024
#define N_  64
#define L_  1024
#define H_  1024
#define NL_ (N_ * L_)

// ---------------------------------------------------------------------------
// K1: dh[n][k] = sum_h ddec[n][h] * Wh[k][h]   (64x1024 output, tiny GEMM)
// ---------------------------------------------------------------------------
__global__ __launch_bounds__(256) void dh_kernel(const float* __restrict__ ddec,
                                                 const float* __restrict__ Wh,
                                                 float* __restrict__ dh) {
    int i = blockIdx.x * 256 + threadIdx.x;   // 0..65535
    int n = i >> 10;
    int k = i & (H_ - 1);
    const float* a = ddec + (size_t)n * H_;
    const float* w = Wh + (size_t)k * H_;
    float acc = 0.f;
#pragma unroll 4
    for (int h = 0; h < H_; h += 4) {
        float4 av = *(const float4*)(a + h);
        float4 wv = *(const float4*)(w + h);
        acc += av.x * wv.x + av.y * wv.y + av.z * wv.z + av.w * wv.w;
    }
    dh[i] = acc;
}

// ---------------------------------------------------------------------------
// K2: fused score GEMM.
//   C[i][k] = sum_h enc[i][h] * Ws[k][h]     (i = n*L + l, both operands [row,K])
//   score[i] += sum_{k in tile} v[k] * tanh(dh[n][k] + C[i][k])
// 64x64 output tile per block, BK=32, 4x4 microtile per thread, fp32 VALU.
// Epilogue reduces over k inside the block and atomicAdds one partial per row.
// ---------------------------------------------------------------------------
#define BK 32
__global__ __launch_bounds__(256) void score_kernel(const float* __restrict__ enc,
                                                    const float* __restrict__ Ws,
                                                    const float* __restrict__ dh,
                                                    const float* __restrict__ v,
                                                    float* __restrict__ score) {
    __shared__ float As[BK][64];   // [h][i-row]
    __shared__ float Bs[BK][64];   // [h][k-row]

    const int i0 = blockIdx.x * 64;   // i-tile base (0..65535), all rows same n
    const int k0 = blockIdx.y * 64;   // k-tile base (0..1023)
    const int t  = threadIdx.x;
    const int tx = t & 15;            // k microtile: cols tx*4..tx*4+3
    const int ty = t >> 4;            // i microtile: rows ty*4..ty*4+3

    float C[4][4] = {};

    for (int h0 = 0; h0 < H_; h0 += BK) {
        __syncthreads();
        // stage 64x32 tiles (transposed to [h][row]); 2 float4 per thread each
#pragma unroll
        for (int f = t; f < 512; f += 256) {
            int r  = f >> 3;
            int c4 = (f & 7) << 2;
            float4 a = *(const float4*)(enc + (size_t)(i0 + r) * H_ + h0 + c4);
            As[c4 + 0][r] = a.x; As[c4 + 1][r] = a.y;
            As[c4 + 2][r] = a.z; As[c4 + 3][r] = a.w;
            float4 b = *(const float4*)(Ws + (size_t)(k0 + r) * H_ + h0 + c4);
            Bs[c4 + 0][r] = b.x; Bs[c4 + 1][r] = b.y;
            Bs[c4 + 2][r] = b.z; Bs[c4 + 3][r] = b.w;
        }
        __syncthreads();
#pragma unroll
        for (int hh = 0; hh < BK; hh++) {
            float a0 = As[hh][ty * 4 + 0];
            float a1 = As[hh][ty * 4 + 1];
            float a2 = As[hh][ty * 4 + 2];
            float a3 = As[hh][ty * 4 + 3];
            float b0 = Bs[hh][tx * 4 + 0];
            float b1 = Bs[hh][tx * 4 + 1];
            float b2 = Bs[hh][tx * 4 + 2];
            float b3 = Bs[hh][tx * 4 + 3];
            C[0][0] += a0 * b0; C[0][1] += a0 * b1; C[0][2] += a0 * b2; C[0][3] += a0 * b3;
            C[1][0] += a1 * b0; C[1][1] += a1 * b1; C[1][2] += a1 * b2; C[1][3] += a1 * b3;
            C[2][0] += a2 * b0; C[2][1] += a2 * b1; C[2][2] += a2 * b2; C[2][3] += a2 * b3;
            C[3][0] += a3 * b0; C[3][1] += a3 * b1; C[3][2] += a3 * b2; C[3][3] += a3 * b3;
        }
    }

    // epilogue: tanh, v-weight, reduce over this block's 64 k-columns
    const int n = i0 >> 10;   // L==1024, so a 64-row i-tile never crosses n
    float dhv[4], vv[4];
#pragma unroll
    for (int c = 0; c < 4; c++) {
        int k = k0 + tx * 4 + c;
        dhv[c] = dh[n * H_ + k];
        vv[c]  = v[k];
    }
#pragma unroll
    for (int r = 0; r < 4; r++) {
        float s = 0.f;
#pragma unroll
        for (int c = 0; c < 4; c++) {
            float x  = dhv[c] + C[r][c];
            float e2 = __expf(2.f * x);           // tanh(x) = 1 - 2/(e^{2x}+1)
            float th = 1.f - 2.f / (e2 + 1.f);    // saturates correctly at +/-1
            s += vv[c] * th;
        }
        // reduce across the 16 tx lanes (same ty => 16 consecutive lanes)
        s += __shfl_xor(s, 1);
        s += __shfl_xor(s, 2);
        s += __shfl_xor(s, 4);
        s += __shfl_xor(s, 8);
        if (tx == 0) atomicAdd(&score[i0 + ty * 4 + r], s);
    }
}

// ---------------------------------------------------------------------------
// K3: masked softmax over L per batch row; writes attn to d_out[65536..]
// ---------------------------------------------------------------------------
__global__ __launch_bounds__(256) void softmax_kernel(const float* __restrict__ score,
                                                      const int* __restrict__ mask,
                                                      float* __restrict__ attn) {
    const int n = blockIdx.x;
    const int t = threadIdx.x;
    __shared__ float redmax[4];
    __shared__ float redsum[4];

    float s[4];
    int   m[4];
    float mymax = -INFINITY;
#pragma unroll
    for (int j = 0; j < 4; j++) {
        int l = t + j * 256;
        m[j] = mask[n * L_ + l];
        s[j] = m[j] ? -INFINITY : score[n * L_ + l];
        mymax = fmaxf(mymax, s[j]);
    }
#pragma unroll
    for (int off = 1; off < 64; off <<= 1)
        mymax = fmaxf(mymax, __shfl_xor(mymax, off));
    if ((t & 63) == 0) redmax[t >> 6] = mymax;
    __syncthreads();
    float gmax = fmaxf(fmaxf(redmax[0], redmax[1]), fmaxf(redmax[2], redmax[3]));

    float e[4];
    float mysum = 0.f;
#pragma unroll
    for (int j = 0; j < 4; j++) {
        e[j] = m[j] ? 0.f : __expf(s[j] - gmax);
        mysum += e[j];
    }
#pragma unroll
    for (int off = 1; off < 64; off <<= 1)
        mysum += __shfl_xor(mysum, off);
    if ((t & 63) == 0) redsum[t >> 6] = mysum;
    __syncthreads();
    float gsum = redsum[0] + redsum[1] + redsum[2] + redsum[3];
    float inv = 1.f / gsum;
#pragma unroll
    for (int j = 0; j < 4; j++)
        attn[n * L_ + t + j * 256] = e[j] * inv;
}

// ---------------------------------------------------------------------------
// K4: context[n][h] = sum_l attn[n][l] * enc[n][l][h]
// ---------------------------------------------------------------------------
__global__ __launch_bounds__(256) void context_kernel(const float* __restrict__ enc,
                                                      const float* __restrict__ attn,
                                                      float* __restrict__ ctx) {
    const int n = blockIdx.x;
    const int h = blockIdx.y * 256 + threadIdx.x;
    __shared__ float w[L_];
#pragma unroll
    for (int j = 0; j < 4; j++)
        w[threadIdx.x + j * 256] = attn[n * L_ + threadIdx.x + j * 256];
    __syncthreads();

    const float* e = enc + (size_t)n * L_ * H_ + h;
    float acc = 0.f;
#pragma unroll 4
    for (int l = 0; l < L_; l++)
        acc += w[l] * e[(size_t)l * H_];
    ctx[n * H_ + h] = acc;
}

// ---------------------------------------------------------------------------
extern "C" void kernel_launch(void* const* d_in, const int* in_sizes, int n_in,
                              void* d_out, int out_size, void* d_ws, size_t ws_size,
                              hipStream_t stream) {
    const float* ddec = (const float*)d_in[0];   // [64,1024] f32
    const float* enc  = (const float*)d_in[1];   // [64,1024,1024] f32
    const int*   mask = (const int*)d_in[2];     // [64,1024] (True = PAD)
    const float* Wh   = (const float*)d_in[3];   // [1024,1024] f32
    const float* Ws   = (const float*)d_in[4];   // [1024,1024] f32
    const float* v    = (const float*)d_in[5];   // [1024] f32

    float* out_ctx  = (float*)d_out;             // [64,1024]
    float* out_attn = out_ctx + N_ * H_;         // [64,1024]

    float* dh    = (float*)d_ws;                 // 64*1024 f32
    float* score = dh + N_ * H_;                 // 64*1024 f32 (atomicAdd target)

    hipMemsetAsync(score, 0, (size_t)NL_ * sizeof(float), stream);

    dh_kernel<<<NL_ / 256, 256, 0, stream>>>(ddec, Wh, dh);

    dim3 g2(NL_ / 64, H_ / 64);
    score_kernel<<<g2, 256, 0, stream>>>(enc, Ws, dh, v, score);

    softmax_kernel<<<N_, 256, 0, stream>>>(score, mask, out_attn);

    dim3 g4(N_, H_ / 256);
    context_kernel<<<g4, 256, 0, stream>>>(enc, out_attn, out_ctx);
}

// Round 2
// 677.002 us; speedup vs baseline: 3.6900x; 3.6900x over previous
//
#include <hip/hip_runtime.h>
#include <hip/hip_bf16.h>
#include <math.h>

// Problem constants: N=64, L=1024, H=1024
#define N_  64
#define L_  1024
#define H_  1024
#define NL_ (N_ * L_)

typedef __attribute__((ext_vector_type(8))) short bf16x8;   // 8 bf16 = 4 VGPRs
typedef __attribute__((ext_vector_type(4))) float f32x4;
typedef unsigned short ushort_t;
typedef unsigned int uint_t;

// ---------------------------------------------------------------------------
// K0: fp32 -> bf16 (RNE) conversion, 8 elements/thread, 16B stores
// ---------------------------------------------------------------------------
__device__ inline ushort_t f32_to_bf16_rne(float f) {
    uint_t u = __float_as_uint(f);
    u += 0x7FFFu + ((u >> 16) & 1u);
    return (ushort_t)(u >> 16);
}

__global__ __launch_bounds__(256) void convert_bf16_kernel(const float* __restrict__ src,
                                                           ushort_t* __restrict__ dst) {
    size_t i = ((size_t)blockIdx.x * 256 + threadIdx.x) * 8;
    float4 a = *(const float4*)(src + i);
    float4 b = *(const float4*)(src + i + 4);
    union { bf16x8 v; ushort_t u[8]; } o;
    o.u[0] = f32_to_bf16_rne(a.x); o.u[1] = f32_to_bf16_rne(a.y);
    o.u[2] = f32_to_bf16_rne(a.z); o.u[3] = f32_to_bf16_rne(a.w);
    o.u[4] = f32_to_bf16_rne(b.x); o.u[5] = f32_to_bf16_rne(b.y);
    o.u[6] = f32_to_bf16_rne(b.z); o.u[7] = f32_to_bf16_rne(b.w);
    *(bf16x8*)(dst + i) = o.v;
}

// ---------------------------------------------------------------------------
// K1: dh[n][k] = sum_h ddec[n][h] * Wh[k][h]   (fp32, tiny: 0.13 GFLOP)
// ---------------------------------------------------------------------------
__global__ __launch_bounds__(256) void dh_kernel(const float* __restrict__ ddec,
                                                 const float* __restrict__ Wh,
                                                 float* __restrict__ dh) {
    int i = blockIdx.x * 256 + threadIdx.x;
    int n = i >> 10;
    const float* a = ddec + (size_t)n * H_;
    const float* w = Wh + (size_t)(i & (H_ - 1)) * H_;
    float acc = 0.f;
#pragma unroll 4
    for (int h = 0; h < H_; h += 4) {
        float4 av = *(const float4*)(a + h);
        float4 wv = *(const float4*)(w + h);
        acc += av.x * wv.x + av.y * wv.y + av.z * wv.z + av.w * wv.w;
    }
    dh[i] = acc;
}

// ---------------------------------------------------------------------------
// K2: MFMA score GEMM (m97 structure).
//   C[i][k] = sum_h enc_bf[i][h] * ws_bf[k][h]   (both row-major, K contiguous)
//   score[i] += sum_k v[k] * tanh(dh[n][k] + C[i][k])
// Tile 128(i) x 128(k), BK=32, 256 thr = 4 waves each 64x64 (4x4 frags of
// 16x16x32). Staging: global_load_lds width=16, LDS chunk-swizzled so
// ds_read_b128 fragments hit the 8-cycle bank minimum.
//
// LDS layout: tile row r (128 rows x 32 bf16) stores its 4 16B-chunks at
//   chunk(r, q) = r*4 + (q ^ ((r>>1)&3))
// Staging lane (issue j, tid): c_lin = j*256+tid -> r=c_lin>>2, c'=c_lin&3,
//   content quad q = c' ^ ((r>>1)&3); LDS dest = wave-uniform base + lane*16.
// Read lane (m = lane&15, q = lane>>4), row r = base+m: swizzle sel reduces
//   to (m>>1)&3 since base is a multiple of 16.
// ---------------------------------------------------------------------------
__device__ inline void stage_tile(const ushort_t* __restrict__ gbase,
                                  ushort_t* lds, int tid, size_t row0_off) {
#pragma unroll
    for (int j = 0; j < 2; j++) {
        int c_lin = j * 256 + tid;
        int r  = c_lin >> 2;
        int cp = c_lin & 3;
        int q  = cp ^ ((r >> 1) & 3);
        const ushort_t* g = gbase + row0_off + (size_t)r * H_ + q * 8;
        ushort_t* l = lds + (size_t)(j * 256 + (tid & ~63)) * 8;  // wave-uniform
        __builtin_amdgcn_global_load_lds((const __attribute__((address_space(1))) void*)g,
                                         (__attribute__((address_space(3))) void*)l,
                                         16, 0, 0);
    }
}

__global__ __launch_bounds__(256) void score_mfma_kernel(const ushort_t* __restrict__ enc_bf,
                                                         const ushort_t* __restrict__ ws_bf,
                                                         const float* __restrict__ dh,
                                                         const float* __restrict__ v,
                                                         float* __restrict__ score) {
    __shared__ ushort_t As[128 * 32];   // 8 KB
    __shared__ ushort_t Bs[128 * 32];   // 8 KB

    const int i0 = blockIdx.x * 128;    // i-tile base (i = n*L + l)
    const int k0 = blockIdx.y * 128;    // k-tile base
    const int tid  = threadIdx.x;
    const int lane = tid & 63;
    const int wv   = tid >> 6;
    const int wr   = (wv >> 1) * 64;    // wave row base in tile
    const int wc   = (wv & 1) * 64;     // wave col base in tile
    const int m    = lane & 15;
    const int q    = lane >> 4;
    const int qs   = q ^ ((m >> 1) & 3);  // swizzled chunk col for reads

    f32x4 acc[4][4];
#pragma unroll
    for (int a = 0; a < 4; a++)
#pragma unroll
        for (int b = 0; b < 4; b++)
            acc[a][b] = (f32x4){0.f, 0.f, 0.f, 0.f};

    for (int h0 = 0; h0 < H_; h0 += 32) {
        __syncthreads();
        stage_tile(enc_bf, As, tid, (size_t)i0 * H_ + h0);
        stage_tile(ws_bf,  Bs, tid, (size_t)k0 * H_ + h0);
        __syncthreads();

        bf16x8 af[4], bfr[4];
#pragma unroll
        for (int ti = 0; ti < 4; ti++) {
            int r = wr + ti * 16 + m;
            af[ti] = *(const bf16x8*)(As + (size_t)(r * 4 + qs) * 8);
        }
#pragma unroll
        for (int tj = 0; tj < 4; tj++) {
            int r = wc + tj * 16 + m;
            bfr[tj] = *(const bf16x8*)(Bs + (size_t)(r * 4 + qs) * 8);
        }
#pragma unroll
        for (int ti = 0; ti < 4; ti++)
#pragma unroll
            for (int tj = 0; tj < 4; tj++)
                acc[ti][tj] = __builtin_amdgcn_mfma_f32_16x16x32_bf16(
                    af[ti], bfr[tj], acc[ti][tj], 0, 0, 0);
    }

    // Epilogue: x = dh + C; s_row += v[k] * tanh(x); reduce over this block's
    // 64 k-columns per wave, one atomicAdd per row per wave.
    const int nb = i0 >> 10;            // batch index (128-row tile never crosses n)
    float vv[4], dhv[4];
#pragma unroll
    for (int tj = 0; tj < 4; tj++) {
        int k = k0 + wc + tj * 16 + m;  // C/D col = lane&15
        vv[tj]  = v[k];
        dhv[tj] = dh[nb * H_ + k];
    }
#pragma unroll
    for (int ti = 0; ti < 4; ti++) {
#pragma unroll
        for (int reg = 0; reg < 4; reg++) {
            float s = 0.f;
#pragma unroll
            for (int tj = 0; tj < 4; tj++) {
                float x  = dhv[tj] + acc[ti][tj][reg];
                float e2 = __expf(2.f * x);
                s += vv[tj] * (1.f - 2.f / (e2 + 1.f));   // tanh, saturates at +/-1
            }
            s += __shfl_xor(s, 1);
            s += __shfl_xor(s, 2);
            s += __shfl_xor(s, 4);
            s += __shfl_xor(s, 8);
            if (m == 0) {
                int i_local = wr + ti * 16 + q * 4 + reg;   // C/D row = quad*4+reg
                atomicAdd(&score[i0 + i_local], s);
            }
        }
    }
}

// ---------------------------------------------------------------------------
// K3: masked softmax over L per batch row; writes attn to d_out[65536..]
// ---------------------------------------------------------------------------
__global__ __launch_bounds__(256) void softmax_kernel(const float* __restrict__ score,
                                                      const int* __restrict__ mask,
                                                      float* __restrict__ attn) {
    const int n = blockIdx.x;
    const int t = threadIdx.x;
    __shared__ float redmax[4];
    __shared__ float redsum[4];

    float s[4];
    int   mk[4];
    float mymax = -INFINITY;
#pragma unroll
    for (int j = 0; j < 4; j++) {
        int l = t + j * 256;
        mk[j] = mask[n * L_ + l];
        s[j] = mk[j] ? -INFINITY : score[n * L_ + l];
        mymax = fmaxf(mymax, s[j]);
    }
#pragma unroll
    for (int off = 1; off < 64; off <<= 1)
        mymax = fmaxf(mymax, __shfl_xor(mymax, off));
    if ((t & 63) == 0) redmax[t >> 6] = mymax;
    __syncthreads();
    float gmax = fmaxf(fmaxf(redmax[0], redmax[1]), fmaxf(redmax[2], redmax[3]));

    float e[4];
    float mysum = 0.f;
#pragma unroll
    for (int j = 0; j < 4; j++) {
        e[j] = mk[j] ? 0.f : __expf(s[j] - gmax);
        mysum += e[j];
    }
#pragma unroll
    for (int off = 1; off < 64; off <<= 1)
        mysum += __shfl_xor(mysum, off);
    if ((t & 63) == 0) redsum[t >> 6] = mysum;
    __syncthreads();
    float gsum = redsum[0] + redsum[1] + redsum[2] + redsum[3];
    float inv = 1.f / gsum;
#pragma unroll
    for (int j = 0; j < 4; j++)
        attn[n * L_ + t + j * 256] = e[j] * inv;
}

// ---------------------------------------------------------------------------
// K4: context[n][h] = sum_l attn[n][l] * enc_bf[n][l][h]  (bf16 enc, fp32 acc)
// grid (64, 4): block handles batch n, h-range [by*256, by*256+256)
// ---------------------------------------------------------------------------
__global__ __launch_bounds__(256) void context_kernel(const ushort_t* __restrict__ enc_bf,
                                                      const float* __restrict__ attn,
                                                      float* __restrict__ ctx) {
    const int n = blockIdx.x;
    const int h = blockIdx.y * 256 + threadIdx.x;
    __shared__ float w[L_];
#pragma unroll
    for (int j = 0; j < 4; j++)
        w[threadIdx.x + j * 256] = attn[n * L_ + threadIdx.x + j * 256];
    __syncthreads();

    const ushort_t* e = enc_bf + (size_t)n * L_ * H_ + h;
    float acc = 0.f;
#pragma unroll 8
    for (int l = 0; l < L_; l++) {
        float x = __uint_as_float(((uint_t)e[(size_t)l * H_]) << 16);
        acc += w[l] * x;
    }
    ctx[n * H_ + h] = acc;
}

// ---------------------------------------------------------------------------
extern "C" void kernel_launch(void* const* d_in, const int* in_sizes, int n_in,
                              void* d_out, int out_size, void* d_ws, size_t ws_size,
                              hipStream_t stream) {
    const float* ddec = (const float*)d_in[0];   // [64,1024] f32
    const float* enc  = (const float*)d_in[1];   // [64,1024,1024] f32
    const int*   mask = (const int*)d_in[2];     // [64,1024]
    const float* Wh   = (const float*)d_in[3];   // [1024,1024] f32
    const float* Ws   = (const float*)d_in[4];   // [1024,1024] f32
    const float* v    = (const float*)d_in[5];   // [1024] f32

    float* out_ctx  = (float*)d_out;             // [64,1024]
    float* out_attn = out_ctx + N_ * H_;         // [64,1024]

    // ws layout: enc_bf (128 MB) | ws_bf (2 MB) | dh (256 KB) | score (256 KB)
    ushort_t* enc_bf = (ushort_t*)d_ws;
    ushort_t* ws_bf  = enc_bf + (size_t)NL_ * H_;
    float*    dh     = (float*)(ws_bf + (size_t)H_ * H_);
    float*    score  = dh + N_ * H_;

    convert_bf16_kernel<<<(size_t)NL_ * H_ / 2048, 256, 0, stream>>>(enc, enc_bf);
    convert_bf16_kernel<<<(size_t)H_ * H_ / 2048, 256, 0, stream>>>(Ws, ws_bf);

    hipMemsetAsync(score, 0, (size_t)NL_ * sizeof(float), stream);

    dh_kernel<<<NL_ / 256, 256, 0, stream>>>(ddec, Wh, dh);

    dim3 g2(NL_ / 128, H_ / 128);
    score_mfma_kernel<<<g2, 256, 0, stream>>>(enc_bf, ws_bf, dh, v, score);

    softmax_kernel<<<N_, 256, 0, stream>>>(score, mask, out_attn);

    dim3 g4(N_, 4);
    context_kernel<<<g4, 256, 0, stream>>>(enc_bf, out_attn, out_ctx);
}

// Round 3
// 659.657 us; speedup vs baseline: 3.7870x; 1.0263x over previous
//
#include <hip/hip_runtime.h>
#include <hip/hip_bf16.h>
#include <math.h>

// Problem constants: N=64, L=1024, H=1024
#define N_  64
#define L_  1024
#define H_  1024
#define NL_ (N_ * L_)

typedef __attribute__((ext_vector_type(8))) short bf16x8;   // 8 bf16 = 4 VGPRs
typedef __attribute__((ext_vector_type(4))) float f32x4;
typedef unsigned short ushort_t;
typedef unsigned int uint_t;

// ---------------------------------------------------------------------------
// K0: fp32 -> bf16 (RNE), grid-strided, 8 elements/thread/iter, 16B stores
// ---------------------------------------------------------------------------
__device__ inline ushort_t f32_to_bf16_rne(float f) {
    uint_t u = __float_as_uint(f);
    u += 0x7FFFu + ((u >> 16) & 1u);
    return (ushort_t)(u >> 16);
}

__global__ __launch_bounds__(256) void convert_bf16_kernel(const float* __restrict__ src,
                                                           ushort_t* __restrict__ dst,
                                                           size_t nvec8) {
    size_t stride = (size_t)gridDim.x * 256;
    for (size_t g = (size_t)blockIdx.x * 256 + threadIdx.x; g < nvec8; g += stride) {
        size_t i = g * 8;
        float4 a = *(const float4*)(src + i);
        float4 b = *(const float4*)(src + i + 4);
        union { bf16x8 v; ushort_t u[8]; } o;
        o.u[0] = f32_to_bf16_rne(a.x); o.u[1] = f32_to_bf16_rne(a.y);
        o.u[2] = f32_to_bf16_rne(a.z); o.u[3] = f32_to_bf16_rne(a.w);
        o.u[4] = f32_to_bf16_rne(b.x); o.u[5] = f32_to_bf16_rne(b.y);
        o.u[6] = f32_to_bf16_rne(b.z); o.u[7] = f32_to_bf16_rne(b.w);
        *(bf16x8*)(dst + i) = o.v;
    }
}

// ---------------------------------------------------------------------------
// K1: dh[n][k] = sum_h ddec[n][h] * Wh[k][h]   (fp32, tiny: 0.13 GFLOP)
// unroll 8 => 16 float4 loads in flight, hides L2 latency
// ---------------------------------------------------------------------------
__global__ __launch_bounds__(256) void dh_kernel(const float* __restrict__ ddec,
                                                 const float* __restrict__ Wh,
                                                 float* __restrict__ dh) {
    int i = blockIdx.x * 256 + threadIdx.x;
    int n = i >> 10;
    const float* a = ddec + (size_t)n * H_;
    const float* w = Wh + (size_t)(i & (H_ - 1)) * H_;
    float acc = 0.f;
#pragma unroll 8
    for (int h = 0; h < H_; h += 4) {
        float4 av = *(const float4*)(a + h);
        float4 wv = *(const float4*)(w + h);
        acc += av.x * wv.x + av.y * wv.y + av.z * wv.z + av.w * wv.w;
    }
    dh[i] = acc;
}

// ---------------------------------------------------------------------------
// K2: MFMA score GEMM (m97 structure).
//   C[i][k] = sum_h enc_bf[i][h] * ws_bf[k][h]   (both row-major, K contiguous)
//   score[i] += sum_k v[k] * tanh(dh[n][k] + C[i][k])
// Tile 128(i) x 128(k), BK=32, 256 thr = 4 waves each 64x64 (4x4 frags of
// 16x16x32). Staging: global_load_lds width=16, LDS chunk-swizzled so
// ds_read_b128 fragments hit the 8-cycle bank minimum.
//
// Grid: 1-D, 4096 blocks. Decode so that the 8 k-tile blocks of each i-tile
// land on the SAME XCD (XCD = blockIdx % 8 round-robin) and are temporally
// adjacent -> enc tile fetched from HBM once, re-served from that XCD's L2:
//   k_tile = (b>>3)&7, i_tile = (b&7) | ((b>>6)<<3)
// ---------------------------------------------------------------------------
__device__ inline void stage_tile(const ushort_t* __restrict__ gbase,
                                  ushort_t* lds, int tid, size_t row0_off) {
#pragma unroll
    for (int j = 0; j < 2; j++) {
        int c_lin = j * 256 + tid;
        int r  = c_lin >> 2;
        int cp = c_lin & 3;
        int q  = cp ^ ((r >> 1) & 3);
        const ushort_t* g = gbase + row0_off + (size_t)r * H_ + q * 8;
        ushort_t* l = lds + (size_t)(j * 256 + (tid & ~63)) * 8;  // wave-uniform
        __builtin_amdgcn_global_load_lds((const __attribute__((address_space(1))) void*)g,
                                         (__attribute__((address_space(3))) void*)l,
                                         16, 0, 0);
    }
}

__global__ __launch_bounds__(256) void score_mfma_kernel(const ushort_t* __restrict__ enc_bf,
                                                         const ushort_t* __restrict__ ws_bf,
                                                         const float* __restrict__ dh,
                                                         const float* __restrict__ v,
                                                         float* __restrict__ score) {
    __shared__ ushort_t As[128 * 32];   // 8 KB
    __shared__ ushort_t Bs[128 * 32];   // 8 KB

    const int b  = blockIdx.x;
    const int i0 = ((b & 7) | ((b >> 6) << 3)) * 128;   // i-tile base
    const int k0 = ((b >> 3) & 7) * 128;                // k-tile base
    const int tid  = threadIdx.x;
    const int lane = tid & 63;
    const int wv   = tid >> 6;
    const int wr   = (wv >> 1) * 64;    // wave row base in tile
    const int wc   = (wv & 1) * 64;     // wave col base in tile
    const int m    = lane & 15;
    const int q    = lane >> 4;
    const int qs   = q ^ ((m >> 1) & 3);  // swizzled chunk col for reads

    f32x4 acc[4][4];
#pragma unroll
    for (int a = 0; a < 4; a++)
#pragma unroll
        for (int c = 0; c < 4; c++)
            acc[a][c] = (f32x4){0.f, 0.f, 0.f, 0.f};

    for (int h0 = 0; h0 < H_; h0 += 32) {
        __syncthreads();
        stage_tile(enc_bf, As, tid, (size_t)i0 * H_ + h0);
        stage_tile(ws_bf,  Bs, tid, (size_t)k0 * H_ + h0);
        __syncthreads();

        bf16x8 af[4], bfr[4];
#pragma unroll
        for (int ti = 0; ti < 4; ti++) {
            int r = wr + ti * 16 + m;
            af[ti] = *(const bf16x8*)(As + (size_t)(r * 4 + qs) * 8);
        }
#pragma unroll
        for (int tj = 0; tj < 4; tj++) {
            int r = wc + tj * 16 + m;
            bfr[tj] = *(const bf16x8*)(Bs + (size_t)(r * 4 + qs) * 8);
        }
#pragma unroll
        for (int ti = 0; ti < 4; ti++)
#pragma unroll
            for (int tj = 0; tj < 4; tj++)
                acc[ti][tj] = __builtin_amdgcn_mfma_f32_16x16x32_bf16(
                    af[ti], bfr[tj], acc[ti][tj], 0, 0, 0);
    }

    // Epilogue: x = dh + C; s_row += v[k] * tanh(x); reduce over this block's
    // 64 k-columns per wave, one atomicAdd per row per wave.
    const int nb = i0 >> 10;            // batch index (128-row tile never crosses n)
    float vv[4], dhv[4];
#pragma unroll
    for (int tj = 0; tj < 4; tj++) {
        int k = k0 + wc + tj * 16 + m;  // C/D col = lane&15
        vv[tj]  = v[k];
        dhv[tj] = dh[nb * H_ + k];
    }
#pragma unroll
    for (int ti = 0; ti < 4; ti++) {
#pragma unroll
        for (int reg = 0; reg < 4; reg++) {
            float s = 0.f;
#pragma unroll
            for (int tj = 0; tj < 4; tj++) {
                float x  = dhv[tj] + acc[ti][tj][reg];
                float e2 = __expf(2.f * x);
                s += vv[tj] * (1.f - 2.f / (e2 + 1.f));   // tanh, saturates at +/-1
            }
            s += __shfl_xor(s, 1);
            s += __shfl_xor(s, 2);
            s += __shfl_xor(s, 4);
            s += __shfl_xor(s, 8);
            if (m == 0) {
                int i_local = wr + ti * 16 + q * 4 + reg;   // C/D row = quad*4+reg
                atomicAdd(&score[i0 + i_local], s);
            }
        }
    }
}

// ---------------------------------------------------------------------------
// K3: masked softmax over L per batch row; writes attn to d_out[65536..]
// ---------------------------------------------------------------------------
__global__ __launch_bounds__(256) void softmax_kernel(const float* __restrict__ score,
                                                      const int* __restrict__ mask,
                                                      float* __restrict__ attn) {
    const int n = blockIdx.x;
    const int t = threadIdx.x;
    __shared__ float redmax[4];
    __shared__ float redsum[4];

    float s[4];
    int   mk[4];
    float mymax = -INFINITY;
#pragma unroll
    for (int j = 0; j < 4; j++) {
        int l = t + j * 256;
        mk[j] = mask[n * L_ + l];
        s[j] = mk[j] ? -INFINITY : score[n * L_ + l];
        mymax = fmaxf(mymax, s[j]);
    }
#pragma unroll
    for (int off = 1; off < 64; off <<= 1)
        mymax = fmaxf(mymax, __shfl_xor(mymax, off));
    if ((t & 63) == 0) redmax[t >> 6] = mymax;
    __syncthreads();
    float gmax = fmaxf(fmaxf(redmax[0], redmax[1]), fmaxf(redmax[2], redmax[3]));

    float e[4];
    float mysum = 0.f;
#pragma unroll
    for (int j = 0; j < 4; j++) {
        e[j] = mk[j] ? 0.f : __expf(s[j] - gmax);
        mysum += e[j];
    }
#pragma unroll
    for (int off = 1; off < 64; off <<= 1)
        mysum += __shfl_xor(mysum, off);
    if ((t & 63) == 0) redsum[t >> 6] = mysum;
    __syncthreads();
    float gsum = redsum[0] + redsum[1] + redsum[2] + redsum[3];
    float inv = 1.f / gsum;
#pragma unroll
    for (int j = 0; j < 4; j++)
        attn[n * L_ + t + j * 256] = e[j] * inv;
}

// ---------------------------------------------------------------------------
// K4: context[n][h] = sum_l attn[n][l] * enc_bf[n][l][h]
// grid (64, 8): block (n, L-chunk of 128); 128 threads, 8 h per thread
// (bf16x8 = 16B/lane, 1KB/wave contiguous). fp32 atomicAdd partials into
// zero-initialized ctx.
// ---------------------------------------------------------------------------
__global__ __launch_bounds__(128) void context_kernel(const ushort_t* __restrict__ enc_bf,
                                                      const float* __restrict__ attn,
                                                      float* __restrict__ ctx) {
    const int n  = blockIdx.x;
    const int l0 = blockIdx.y * 128;
    const int t  = threadIdx.x;      // 0..127
    const int h0 = t * 8;

    __shared__ float w[128];
    w[t] = attn[n * L_ + l0 + t];
    __syncthreads();

    const ushort_t* base = enc_bf + (size_t)n * L_ * H_ + (size_t)l0 * H_ + h0;
    float acc[8] = {};
#pragma unroll 4
    for (int l = 0; l < 128; l++) {
        union { bf16x8 v; ushort_t u[8]; } e;
        e.v = *(const bf16x8*)(base + (size_t)l * H_);
        float wl = w[l];
#pragma unroll
        for (int j = 0; j < 8; j++)
            acc[j] += wl * __uint_as_float(((uint_t)e.u[j]) << 16);
    }
#pragma unroll
    for (int j = 0; j < 8; j++)
        atomicAdd(&ctx[n * H_ + h0 + j], acc[j]);
}

// ---------------------------------------------------------------------------
extern "C" void kernel_launch(void* const* d_in, const int* in_sizes, int n_in,
                              void* d_out, int out_size, void* d_ws, size_t ws_size,
                              hipStream_t stream) {
    const float* ddec = (const float*)d_in[0];   // [64,1024] f32
    const float* enc  = (const float*)d_in[1];   // [64,1024,1024] f32
    const int*   mask = (const int*)d_in[2];     // [64,1024]
    const float* Wh   = (const float*)d_in[3];   // [1024,1024] f32
    const float* Ws   = (const float*)d_in[4];   // [1024,1024] f32
    const float* v    = (const float*)d_in[5];   // [1024] f32

    float* out_ctx  = (float*)d_out;             // [64,1024]
    float* out_attn = out_ctx + N_ * H_;         // [64,1024]

    // ws layout: enc_bf (128 MB) | ws_bf (2 MB) | dh (256 KB) | score (256 KB)
    ushort_t* enc_bf = (ushort_t*)d_ws;
    ushort_t* ws_bf  = enc_bf + (size_t)NL_ * H_;
    float*    dh     = (float*)(ws_bf + (size_t)H_ * H_);
    float*    score  = dh + N_ * H_;

    convert_bf16_kernel<<<4096, 256, 0, stream>>>(enc, enc_bf, (size_t)NL_ * H_ / 8);
    convert_bf16_kernel<<<512, 256, 0, stream>>>(Ws, ws_bf, (size_t)H_ * H_ / 8);

    hipMemsetAsync(score, 0, (size_t)NL_ * sizeof(float), stream);
    hipMemsetAsync(out_ctx, 0, (size_t)N_ * H_ * sizeof(float), stream);

    dh_kernel<<<NL_ / 256, 256, 0, stream>>>(ddec, Wh, dh);

    score_mfma_kernel<<<4096, 256, 0, stream>>>(enc_bf, ws_bf, dh, v, score);

    softmax_kernel<<<N_, 256, 0, stream>>>(score, mask, out_attn);

    dim3 g4(N_, 8);
    context_kernel<<<g4, 128, 0, stream>>>(enc_bf, out_attn, out_ctx);
}